// Round 1
// baseline (793.228 us; speedup 1.0000x reference)
//
#include <hip/hip_runtime.h>
#include <hip/hip_bf16.h>

// Problem constants
#define BB 128
#define SS 200
#define HH 512
#define EE 256
#define VV 50000
#define KGRU 1280   // E + 2H
#define KOUT 1792   // 3H + E
#define N3H 1536

typedef __bf16 bf16x8 __attribute__((ext_vector_type(8)));
typedef __bf16 bf16x4 __attribute__((ext_vector_type(4)));
typedef float  f32x4  __attribute__((ext_vector_type(4)));

// ---------------- u2 = attn_w[:,512:1536]^T @ v  (1024 outputs) ----------------
__global__ __launch_bounds__(256) void u2_kernel(const float* __restrict__ attn_w,
                                                 const float* __restrict__ v,
                                                 float* __restrict__ u2) {
    int j = blockIdx.x * 256 + threadIdx.x;   // 0..1023
    float acc = 0.f;
    #pragma unroll 8
    for (int h = 0; h < HH; h++)
        acc += v[h] * attn_w[h * N3H + HH + j];
    u2[j] = acc;
}

// ---------------- embedding gather -> bf16 slots ----------------
__global__ __launch_bounds__(256) void embx_kernel(const int* __restrict__ x,
                                                   const float* __restrict__ emb,
                                                   __bf16* __restrict__ Agru,
                                                   __bf16* __restrict__ Aout) {
    int b = blockIdx.x, e = threadIdx.x;      // E = 256
    float val = emb[(size_t)x[b] * EE + e];
    Aout[(size_t)b * KOUT + 3 * HH + e] = (__bf16)val;          // to_out: emb raw
    Agru[(size_t)b * KGRU + e]          = (__bf16)fmaxf(val, 0.f); // to_gru: relu(emb)
}

// ---------------- h0 -> bf16 ----------------
__global__ __launch_bounds__(256) void h0cast_kernel(const float* __restrict__ h0,
                                                     __bf16* __restrict__ Ah0) {
    int i = blockIdx.x * 256 + threadIdx.x;   // 65536
    Ah0[i] = (__bf16)h0[i];
}

// ---------------- attention: scores -> softmax -> context (one block per b) ----------------
__global__ __launch_bounds__(256) void attn_kernel(const float* __restrict__ enc,
                                                   const float* __restrict__ u2,
                                                   float* __restrict__ context,
                                                   __bf16* __restrict__ Agru,
                                                   __bf16* __restrict__ Aout) {
    __shared__ float u2s[2 * HH];
    __shared__ float sc[SS];
    __shared__ float red[8];
    const int b = blockIdx.x, tid = threadIdx.x;
    const int wave = tid >> 6, lane = tid & 63;

    ((float4*)u2s)[tid] = ((const float4*)u2)[tid];   // 256 * 4 = 1024 floats
    __syncthreads();

    const float* encb = enc + (size_t)b * SS * 2 * HH;
    // pass 1: scores
    for (int s = wave; s < SS; s += 4) {
        const float4* row = (const float4*)(encb + s * 2 * HH);
        float acc = 0.f;
        #pragma unroll
        for (int i = 0; i < 4; i++) {
            float4 e = row[lane + i * 64];
            float4 u = ((const float4*)u2s)[lane + i * 64];
            acc += e.x * u.x + e.y * u.y + e.z * u.z + e.w * u.w;
        }
        #pragma unroll
        for (int off = 32; off; off >>= 1) acc += __shfl_xor(acc, off);
        if (lane == 0) sc[s] = acc;
    }
    __syncthreads();

    // softmax over 200 entries
    float vv = (tid < SS) ? sc[tid] : -3.4e38f;
    float m = vv;
    #pragma unroll
    for (int off = 32; off; off >>= 1) m = fmaxf(m, __shfl_xor(m, off));
    if (lane == 0) red[wave] = m;
    __syncthreads();
    m = fmaxf(fmaxf(red[0], red[1]), fmaxf(red[2], red[3]));
    float p = (tid < SS) ? __expf(vv - m) : 0.f;
    float ssum = p;
    #pragma unroll
    for (int off = 32; off; off >>= 1) ssum += __shfl_xor(ssum, off);
    if (lane == 0) red[4 + wave] = ssum;
    __syncthreads();
    float tot = red[4] + red[5] + red[6] + red[7];
    if (tid < SS) sc[tid] = p / tot;
    __syncthreads();

    // pass 2: context[d] = sum_s p[s] * enc[b,s,d]
    float accd[4] = {0.f, 0.f, 0.f, 0.f};
    for (int s = 0; s < SS; s++) {
        float ps = sc[s];
        const float* row = encb + s * 2 * HH;
        #pragma unroll
        for (int i = 0; i < 4; i++) accd[i] += ps * row[tid + i * 256];
    }
    #pragma unroll
    for (int i = 0; i < 4; i++) {
        int d = tid + i * 256;
        float c = accd[i];
        context[(size_t)b * 2 * HH + d] = c;
        Aout[(size_t)b * KOUT + HH + d] = (__bf16)c;               // to_out: context raw
        Agru[(size_t)b * KGRU + EE + d] = (__bf16)fmaxf(c, 0.f);   // to_gru: relu(context)
    }
}

// ---------------- generic MFMA GEMM: C[128,N] = A[128,K](bf16) @ B[N,K](f32)^T + bias ----------------
// tiles: BM=128, BN=64, BK=32; 256 threads = 4 waves; wave w owns n-cols [w*16, w*16+16)
__global__ __launch_bounds__(256) void gemm_bf16(const __bf16* __restrict__ A,
                                                 const float* __restrict__ B,
                                                 const float* __restrict__ bias,
                                                 float* __restrict__ C,
                                                 int N, int K) {
    __shared__ __bf16 As[128][40];   // +8 pad: rotates banks, keeps 16B align
    __shared__ __bf16 Bs[64][40];
    const int tid = threadIdx.x;
    const int wave = tid >> 6, lane = tid & 63;
    const int q = lane >> 4, r16 = lane & 15;
    const int n0 = blockIdx.x * 64;
    const int am = tid >> 1, ah = tid & 1;  // A staging: 2 threads/row, 16 bf16 each

    f32x4 acc[8];
    #pragma unroll
    for (int mt = 0; mt < 8; mt++) acc[mt] = f32x4{0.f, 0.f, 0.f, 0.f};

    for (int kc = 0; kc < K; kc += 32) {
        // stage A chunk (bf16, direct copy)
        const uint4* ap = (const uint4*)(A + (size_t)am * K + kc + ah * 16);
        uint4 a0 = ap[0], a1 = ap[1];
        *(uint4*)(&As[am][ah * 16])     = a0;
        *(uint4*)(&As[am][ah * 16 + 8]) = a1;
        // stage B chunk (f32 -> bf16): 512 float4 across 256 threads
        #pragma unroll
        for (int j = 0; j < 2; j++) {
            int idx = tid + j * 256;
            int row = idx >> 3, col = (idx & 7) * 4;
            float4 bv = make_float4(0.f, 0.f, 0.f, 0.f);
            if (n0 + row < N)
                bv = *(const float4*)(B + (size_t)(n0 + row) * K + kc + col);
            bf16x4 pk = { (__bf16)bv.x, (__bf16)bv.y, (__bf16)bv.z, (__bf16)bv.w };
            *(bf16x4*)(&Bs[row][col]) = pk;
        }
        __syncthreads();

        bf16x8 bfrag = *(const bf16x8*)(&Bs[wave * 16 + r16][q * 8]);
        #pragma unroll
        for (int mt = 0; mt < 8; mt++) {
            bf16x8 afrag = *(const bf16x8*)(&As[mt * 16 + r16][q * 8]);
            acc[mt] = __builtin_amdgcn_mfma_f32_16x16x32_bf16(afrag, bfrag, acc[mt], 0, 0, 0);
        }
        __syncthreads();
    }

    const int n = n0 + wave * 16 + r16;
    if (n < N) {
        float bv = bias[n];
        #pragma unroll
        for (int mt = 0; mt < 8; mt++)
            #pragma unroll
            for (int i = 0; i < 4; i++) {
                int mrow = mt * 16 + q * 4 + i;
                C[(size_t)mrow * N + n] = acc[mt][i] + bv;
            }
    }
}

// ---------------- GRU gates ----------------
__global__ __launch_bounds__(256) void gate_kernel(const float* __restrict__ gi,
                                                   const float* __restrict__ gh,
                                                   const float* __restrict__ h0,
                                                   float* __restrict__ hout,
                                                   __bf16* __restrict__ Aout) {
    int i = blockIdx.x * 256 + threadIdx.x;   // 65536
    int b = i >> 9, h = i & 511;
    const float* gib = gi + (size_t)b * N3H;
    const float* ghb = gh + (size_t)b * N3H;
    float r = 1.f / (1.f + __expf(-(gib[h] + ghb[h])));
    float z = 1.f / (1.f + __expf(-(gib[HH + h] + ghb[HH + h])));
    float n = tanhf(gib[2 * HH + h] + r * ghb[2 * HH + h]);
    float hnew = (1.f - z) * n + z * h0[i];
    hout[i] = hnew;
    Aout[(size_t)b * KOUT + h] = (__bf16)hnew;   // to_out: h_new
}

extern "C" void kernel_launch(void* const* d_in, const int* in_sizes, int n_in,
                              void* d_out, int out_size, void* d_ws, size_t ws_size,
                              hipStream_t stream) {
    const int*   x      = (const int*)  d_in[0];
    const float* hidden = (const float*)d_in[1];
    const float* enc    = (const float*)d_in[2];
    const float* emb    = (const float*)d_in[3];
    const float* attn_w = (const float*)d_in[4];
    // d_in[5] = attn_b (softmax-invariant, unused)
    const float* v      = (const float*)d_in[6];
    const float* w_ih   = (const float*)d_in[7];
    const float* w_hh   = (const float*)d_in[8];
    const float* b_ih   = (const float*)d_in[9];
    const float* b_hh   = (const float*)d_in[10];
    const float* out_w  = (const float*)d_in[11];
    const float* out_b  = (const float*)d_in[12];

    float* out = (float*)d_out;
    float* logits = out;                       // [128, 50000]
    float* hnew_out = out + (size_t)BB * VV;   // [1, 128, 512]

    // workspace carve (all offsets 16B-aligned)
    char* ws = (char*)d_ws;
    float*  u2      = (float*) (ws + 0);          //  1024 f32
    float*  context = (float*) (ws + 4096);       //  128*1024 f32
    float*  gi      = (float*) (ws + 528384);     //  128*1536 f32
    float*  gh      = (float*) (ws + 1314816);    //  128*1536 f32
    __bf16* Agru    = (__bf16*)(ws + 2101248);    //  128*1280 bf16
    __bf16* Ah0     = (__bf16*)(ws + 2428928);    //  128*512  bf16
    __bf16* Aout    = (__bf16*)(ws + 2560000);    //  128*1792 bf16

    u2_kernel<<<4, 256, 0, stream>>>(attn_w, v, u2);
    embx_kernel<<<BB, 256, 0, stream>>>(x, emb, Agru, Aout);
    h0cast_kernel<<<BB * HH / 256, 256, 0, stream>>>(hidden, Ah0);
    attn_kernel<<<BB, 256, 0, stream>>>(enc, u2, context, Agru, Aout);
    gemm_bf16<<<N3H / 64, 256, 0, stream>>>(Agru, w_ih, b_ih, gi, N3H, KGRU);
    gemm_bf16<<<N3H / 64, 256, 0, stream>>>(Ah0, w_hh, b_hh, gh, N3H, HH);
    gate_kernel<<<BB * HH / 256, 256, 0, stream>>>(gi, gh, hidden, hnew_out, Aout);
    gemm_bf16<<<(VV + 63) / 64, 256, 0, stream>>>(Aout, out_w, out_b, logits, VV, KOUT);
}

// Round 2
// 699.146 us; speedup vs baseline: 1.1346x; 1.1346x over previous
//
#include <hip/hip_runtime.h>
#include <hip/hip_bf16.h>

// Problem constants
#define BB 128
#define SS 200
#define HH 512
#define EE 256
#define VV 50000
#define KGRU 1280   // E + 2H
#define KOUT 1792   // 3H + E
#define N3H 1536

typedef __bf16 bf16x8 __attribute__((ext_vector_type(8)));
typedef __bf16 bf16x4 __attribute__((ext_vector_type(4)));
typedef float  f32x4  __attribute__((ext_vector_type(4)));

// ---------------- u2 = attn_w[:,512:1536]^T @ v  (1024 outputs) ----------------
// 16 blocks x 256 thr: block covers 64 j; wave w covers h-chunk [w*128,(w+1)*128)
__global__ __launch_bounds__(256) void u2_kernel(const float* __restrict__ attn_w,
                                                 const float* __restrict__ v,
                                                 float* __restrict__ u2) {
    __shared__ float part[4][64];
    const int tid = threadIdx.x, wave = tid >> 6, lane = tid & 63;
    const int j = blockIdx.x * 64 + lane;
    const int h0 = wave * 128;
    float acc = 0.f;
    #pragma unroll 8
    for (int h = 0; h < 128; h++)
        acc += v[h0 + h] * attn_w[(size_t)(h0 + h) * N3H + HH + j];
    part[wave][lane] = acc;
    __syncthreads();
    if (wave == 0)
        u2[j] = part[0][lane] + part[1][lane] + part[2][lane] + part[3][lane];
}

// ---------------- prep: embedding gather + h0 cast (one block per b) ----------------
__global__ __launch_bounds__(256) void prep_kernel(const int* __restrict__ x,
                                                   const float* __restrict__ emb,
                                                   const float* __restrict__ h0,
                                                   __bf16* __restrict__ Agru,
                                                   __bf16* __restrict__ Aout,
                                                   __bf16* __restrict__ Ah0) {
    const int b = blockIdx.x, t = threadIdx.x;
    float val = emb[(size_t)x[b] * EE + t];
    Aout[(size_t)b * KOUT + 3 * HH + t] = (__bf16)val;
    Agru[(size_t)b * KGRU + t]          = (__bf16)fmaxf(val, 0.f);
    Ah0[(size_t)b * HH + t]       = (__bf16)h0[(size_t)b * HH + t];
    Ah0[(size_t)b * HH + t + 256] = (__bf16)h0[(size_t)b * HH + t + 256];
}

// ---------------- scores[b,s] = enc[b,s,:] . u2 ----------------
// 512 blocks: block (b, squarter); wave w does s = s0+w, s0+w+4, ...
__global__ __launch_bounds__(256) void scores_kernel(const float* __restrict__ enc,
                                                     const float* __restrict__ u2,
                                                     float* __restrict__ scores) {
    __shared__ float u2s[2 * HH];
    const int tid = threadIdx.x, wave = tid >> 6, lane = tid & 63;
    const int b = blockIdx.x >> 2, s0 = (blockIdx.x & 3) * 50;
    ((float4*)u2s)[tid] = ((const float4*)u2)[tid];
    __syncthreads();
    const float* encb = enc + (size_t)b * SS * 2 * HH;
    for (int s = s0 + wave; s < s0 + 50; s += 4) {
        const float4* row = (const float4*)(encb + s * 2 * HH);
        float acc = 0.f;
        #pragma unroll
        for (int i = 0; i < 4; i++) {
            float4 e = row[lane + i * 64];
            float4 u = ((const float4*)u2s)[lane + i * 64];
            acc += e.x * u.x + e.y * u.y + e.z * u.z + e.w * u.w;
        }
        #pragma unroll
        for (int off = 32; off; off >>= 1) acc += __shfl_xor(acc, off);
        if (lane == 0) scores[b * SS + s] = acc;
    }
}

// ---------------- softmax + context (block = (b, dhalf of 512)) ----------------
__global__ __launch_bounds__(256) void ctx_kernel(const float* __restrict__ enc,
                                                  const float* __restrict__ scores,
                                                  __bf16* __restrict__ Agru,
                                                  __bf16* __restrict__ Aout) {
    __shared__ float sc[SS];
    __shared__ float red[8];
    const int tid = threadIdx.x, wave = tid >> 6, lane = tid & 63;
    const int b = blockIdx.x >> 1, d0 = (blockIdx.x & 1) * 512;

    float vv = (tid < SS) ? scores[b * SS + tid] : -3.4e38f;
    float m = vv;
    #pragma unroll
    for (int off = 32; off; off >>= 1) m = fmaxf(m, __shfl_xor(m, off));
    if (lane == 0) red[wave] = m;
    __syncthreads();
    m = fmaxf(fmaxf(red[0], red[1]), fmaxf(red[2], red[3]));
    float p = (tid < SS) ? __expf(vv - m) : 0.f;
    float ssum = p;
    #pragma unroll
    for (int off = 32; off; off >>= 1) ssum += __shfl_xor(ssum, off);
    if (lane == 0) red[4 + wave] = ssum;
    __syncthreads();
    float tot = red[4] + red[5] + red[6] + red[7];
    if (tid < SS) sc[tid] = p / tot;
    __syncthreads();

    const float* encb = enc + (size_t)b * SS * 2 * HH + d0;
    float a0 = 0.f, a1 = 0.f;
    for (int s = 0; s < SS; s += 4) {
        #pragma unroll
        for (int k = 0; k < 4; k++) {
            float ps = sc[s + k];
            const float* row = encb + (s + k) * 2 * HH;
            a0 += ps * row[tid];
            a1 += ps * row[tid + 256];
        }
    }
    int d = d0 + tid;
    Aout[(size_t)b * KOUT + HH + d]       = (__bf16)a0;
    Agru[(size_t)b * KGRU + EE + d]       = (__bf16)fmaxf(a0, 0.f);
    Aout[(size_t)b * KOUT + HH + d + 256] = (__bf16)a1;
    Agru[(size_t)b * KGRU + EE + d + 256] = (__bf16)fmaxf(a1, 0.f);
}

// ---------------- merged GRU GEMMs: blocks 0..23 -> gi, 24..47 -> gh (BM=128,BN=64,BK=32) ----------------
__global__ __launch_bounds__(256) void gru_gemms(const __bf16* __restrict__ Agru,
                                                 const float* __restrict__ w_ih,
                                                 const float* __restrict__ b_ih,
                                                 float* __restrict__ gi,
                                                 const __bf16* __restrict__ Ah0,
                                                 const float* __restrict__ w_hh,
                                                 const float* __restrict__ b_hh,
                                                 float* __restrict__ gh) {
    __shared__ __bf16 As[128][40];
    __shared__ __bf16 Bs[64][40];
    const bool second = blockIdx.x >= 24;
    const __bf16* A   = second ? Ah0  : Agru;
    const float*  B   = second ? w_hh : w_ih;
    const float*  bias= second ? b_hh : b_ih;
    float*        C   = second ? gh   : gi;
    const int K = second ? HH : KGRU;
    const int n0 = (blockIdx.x - (second ? 24 : 0)) * 64;

    const int tid = threadIdx.x, wave = tid >> 6, lane = tid & 63;
    const int q = lane >> 4, r16 = lane & 15;
    const int am = tid >> 1, ah = tid & 1;

    f32x4 acc[8];
    #pragma unroll
    for (int mt = 0; mt < 8; mt++) acc[mt] = f32x4{0.f, 0.f, 0.f, 0.f};

    for (int kc = 0; kc < K; kc += 32) {
        const uint4* ap = (const uint4*)(A + (size_t)am * K + kc + ah * 16);
        uint4 a0 = ap[0], a1 = ap[1];
        *(uint4*)(&As[am][ah * 16])     = a0;
        *(uint4*)(&As[am][ah * 16 + 8]) = a1;
        #pragma unroll
        for (int j = 0; j < 2; j++) {
            int idx = tid + j * 256;
            int row = idx >> 3, col = (idx & 7) * 4;
            float4 bv = *(const float4*)(B + (size_t)(n0 + row) * K + kc + col);
            bf16x4 pk = { (__bf16)bv.x, (__bf16)bv.y, (__bf16)bv.z, (__bf16)bv.w };
            *(bf16x4*)(&Bs[row][col]) = pk;
        }
        __syncthreads();
        bf16x8 bfrag = *(const bf16x8*)(&Bs[wave * 16 + r16][q * 8]);
        #pragma unroll
        for (int mt = 0; mt < 8; mt++) {
            bf16x8 afrag = *(const bf16x8*)(&As[mt * 16 + r16][q * 8]);
            acc[mt] = __builtin_amdgcn_mfma_f32_16x16x32_bf16(afrag, bfrag, acc[mt], 0, 0, 0);
        }
        __syncthreads();
    }
    const int n = n0 + wave * 16 + r16;
    float bv = bias[n];
    #pragma unroll
    for (int mt = 0; mt < 8; mt++)
        #pragma unroll
        for (int i = 0; i < 4; i++)
            C[(size_t)(mt * 16 + q * 4 + i) * N3H + n] = acc[mt][i] + bv;
}

// ---------------- GRU gates ----------------
__global__ __launch_bounds__(256) void gate_kernel(const float* __restrict__ gi,
                                                   const float* __restrict__ gh,
                                                   const float* __restrict__ h0,
                                                   float* __restrict__ hout,
                                                   __bf16* __restrict__ Aout) {
    int i = blockIdx.x * 256 + threadIdx.x;   // 65536
    int b = i >> 9, h = i & 511;
    const float* gib = gi + (size_t)b * N3H;
    const float* ghb = gh + (size_t)b * N3H;
    float r = 1.f / (1.f + __expf(-(gib[h] + ghb[h])));
    float z = 1.f / (1.f + __expf(-(gib[HH + h] + ghb[HH + h])));
    float n = tanhf(gib[2 * HH + h] + r * ghb[2 * HH + h]);
    float hnew = (1.f - z) * n + z * h0[i];
    hout[i] = hnew;
    Aout[(size_t)b * KOUT + h] = (__bf16)hnew;
}

// ---------------- logits GEMM: 128x128 tile, BK=32, 4 waves (wave owns 32 n-cols) ----------------
__global__ __launch_bounds__(256, 3) void gemm128(const __bf16* __restrict__ A,
                                                  const float* __restrict__ B,
                                                  const float* __restrict__ bias,
                                                  float* __restrict__ C,
                                                  int N, int K) {
    __shared__ __bf16 As[128][40];
    __shared__ __bf16 Bs[128][40];
    const int tid = threadIdx.x, wave = tid >> 6, lane = tid & 63;
    const int q = lane >> 4, r16 = lane & 15;
    const int n0 = blockIdx.x * 128;
    const int row = tid >> 1, half = tid & 1;

    f32x4 acc[8][2];
    #pragma unroll
    for (int mt = 0; mt < 8; mt++) {
        acc[mt][0] = f32x4{0.f, 0.f, 0.f, 0.f};
        acc[mt][1] = f32x4{0.f, 0.f, 0.f, 0.f};
    }

    const bool brow_ok = (n0 + row) < N;
    for (int kc = 0; kc < K; kc += 32) {
        const uint4* ap = (const uint4*)(A + (size_t)row * K + kc + half * 16);
        uint4 a0 = ap[0], a1 = ap[1];
        float4 bv[4];
        const float* bp = B + (size_t)(n0 + row) * K + kc + half * 16;
        #pragma unroll
        for (int i = 0; i < 4; i++)
            bv[i] = brow_ok ? *(const float4*)(bp + i * 4) : make_float4(0.f, 0.f, 0.f, 0.f);
        *(uint4*)(&As[row][half * 16])     = a0;
        *(uint4*)(&As[row][half * 16 + 8]) = a1;
        #pragma unroll
        for (int i = 0; i < 4; i++) {
            bf16x4 pk = { (__bf16)bv[i].x, (__bf16)bv[i].y, (__bf16)bv[i].z, (__bf16)bv[i].w };
            *(bf16x4*)(&Bs[row][half * 16 + i * 4]) = pk;
        }
        __syncthreads();
        bf16x8 bfrag0 = *(const bf16x8*)(&Bs[wave * 32 + r16][q * 8]);
        bf16x8 bfrag1 = *(const bf16x8*)(&Bs[wave * 32 + 16 + r16][q * 8]);
        #pragma unroll
        for (int mt = 0; mt < 8; mt++) {
            bf16x8 afrag = *(const bf16x8*)(&As[mt * 16 + r16][q * 8]);
            acc[mt][0] = __builtin_amdgcn_mfma_f32_16x16x32_bf16(afrag, bfrag0, acc[mt][0], 0, 0, 0);
            acc[mt][1] = __builtin_amdgcn_mfma_f32_16x16x32_bf16(afrag, bfrag1, acc[mt][1], 0, 0, 0);
        }
        __syncthreads();
    }

    #pragma unroll
    for (int j = 0; j < 2; j++) {
        int n = n0 + wave * 32 + j * 16 + r16;
        if (n < N) {
            float bvv = bias[n];
            #pragma unroll
            for (int mt = 0; mt < 8; mt++)
                #pragma unroll
                for (int i = 0; i < 4; i++)
                    C[(size_t)(mt * 16 + q * 4 + i) * N + n] = acc[mt][j][i] + bvv;
        }
    }
}

extern "C" void kernel_launch(void* const* d_in, const int* in_sizes, int n_in,
                              void* d_out, int out_size, void* d_ws, size_t ws_size,
                              hipStream_t stream) {
    const int*   x      = (const int*)  d_in[0];
    const float* hidden = (const float*)d_in[1];
    const float* enc    = (const float*)d_in[2];
    const float* emb    = (const float*)d_in[3];
    const float* attn_w = (const float*)d_in[4];
    // d_in[5] = attn_b (softmax-invariant, unused)
    const float* v      = (const float*)d_in[6];
    const float* w_ih   = (const float*)d_in[7];
    const float* w_hh   = (const float*)d_in[8];
    const float* b_ih   = (const float*)d_in[9];
    const float* b_hh   = (const float*)d_in[10];
    const float* out_w  = (const float*)d_in[11];
    const float* out_b  = (const float*)d_in[12];

    float* out = (float*)d_out;
    float* logits = out;                       // [128, 50000]
    float* hnew_out = out + (size_t)BB * VV;   // [1, 128, 512]

    char* ws = (char*)d_ws;
    float*  u2      = (float*) (ws + 0);          // 1024 f32
    float*  scores  = (float*) (ws + 4096);       // 128*200 f32
    float*  gi      = (float*) (ws + 106496);     // 128*1536 f32
    float*  gh      = (float*) (ws + 892928);     // 128*1536 f32
    __bf16* Agru    = (__bf16*)(ws + 1679360);    // 128*1280 bf16
    __bf16* Ah0     = (__bf16*)(ws + 2007040);    // 128*512  bf16
    __bf16* Aout    = (__bf16*)(ws + 2138112);    // 128*1792 bf16

    u2_kernel<<<16, 256, 0, stream>>>(attn_w, v, u2);
    prep_kernel<<<BB, 256, 0, stream>>>(x, emb, hidden, Agru, Aout, Ah0);
    scores_kernel<<<BB * 4, 256, 0, stream>>>(enc, u2, scores);
    ctx_kernel<<<BB * 2, 256, 0, stream>>>(enc, scores, Agru, Aout);
    gru_gemms<<<48, 256, 0, stream>>>(Agru, w_ih, b_ih, gi, Ah0, w_hh, b_hh, gh);
    gate_kernel<<<BB * HH / 256, 256, 0, stream>>>(gi, gh, hidden, hnew_out, Aout);
    gemm128<<<(VV + 127) / 128, 256, 0, stream>>>(Aout, out_w, out_b, logits, VV, KOUT);
}